// Round 8
// baseline (563.405 us; speedup 1.0000x reference)
//
#include <hip/hip_runtime.h>
#include <hip/hip_bf16.h>

#define NB 16
#define NN 4096
#define NPTS 512
#define NSAMP 64
#define BN_EPS 1e-5f
#define INV_BN (1.0f / 65536.0f)
#define NFPS 16
#define NWRK 128
#define NBLK (NFPS + NWRK)

// 82 KB LDS/block -> 1 block/CU guaranteed (2x82 > 160KB).
// fps: [0,65536) float4 coords, +65536 slots u64[2][8], +65664 lds_cent int[32].
// workers: [0,32768) W, +32768 bias, +33280 AC, +34304 red.
#define SMEM_BYTES 83968

__device__ __forceinline__ void gbar(int* arrive, int target) {
    __syncthreads();
    if (threadIdx.x == 0) {
        __threadfence();
        atomicAdd(arrive, 1);
        while (__hip_atomic_load(arrive, __ATOMIC_RELAXED,
                                 __HIP_MEMORY_SCOPE_AGENT) < target)
            __builtin_amdgcn_s_sleep(2);
        __threadfence();
    }
    __syncthreads();
}

// wave64 unsigned-max via DPP: row_shr 1/2/4/8 + row_bcast 15/31.
// bound_ctrl=true fills 0 (identity for unsigned max). Valid in lane 63.
__device__ __forceinline__ unsigned wave_max_dpp(unsigned x) {
    unsigned o;
    o = (unsigned)__builtin_amdgcn_mov_dpp((int)x, 0x111, 0xF, 0xF, true); x = o > x ? o : x;
    o = (unsigned)__builtin_amdgcn_mov_dpp((int)x, 0x112, 0xF, 0xF, true); x = o > x ? o : x;
    o = (unsigned)__builtin_amdgcn_mov_dpp((int)x, 0x114, 0xF, 0xF, true); x = o > x ? o : x;
    o = (unsigned)__builtin_amdgcn_mov_dpp((int)x, 0x118, 0xF, 0xF, true); x = o > x ? o : x;
    o = (unsigned)__builtin_amdgcn_mov_dpp((int)x, 0x142, 0xF, 0xF, true); x = o > x ? o : x;
    o = (unsigned)__builtin_amdgcn_mov_dpp((int)x, 0x143, 0xF, 0xF, true); x = o > x ? o : x;
    return x;
}

// ---------------------------------------------------------------------------
// FPS (blocks 0..15): round-5 structure (8 waves x 8 pts/thread). ONLY change
// vs round 5: cent publish via LDS ring + 16-entry batched flush by wave 3
// lane 0 (int4 x4 + RELEASE prog[b]) -> no per-step global store/vmcnt drain.
// Exact numpy semantics: _rn dist ops, strict-> first-occurrence argmax,
// key (dist<<32)|(4095-idx).
// ---------------------------------------------------------------------------
__device__ void fps_body(const float* __restrict__ coord, int* __restrict__ cent,
                         int* __restrict__ prog, unsigned char* sm) {
    float4* sc = (float4*)sm;
    unsigned long long* slot = (unsigned long long*)(sm + 65536);  // [2][8]
    int* lds_cent = (int*)(sm + 65664);                            // 32 ints
    const int b = blockIdx.x;
    const float* cb = coord + (size_t)b * NN * 3;
    const int t = threadIdx.x;

    for (int i = t; i < NN; i += 512)
        sc[i] = make_float4(cb[3 * i], cb[3 * i + 1], cb[3 * i + 2], 0.0f);

    float x[8], y[8], z[8], dist[8];
    {
        const float4* g = (const float4*)(cb + 24 * t);   // 96B, 16B-aligned
        const float4 v0 = g[0], v1 = g[1], v2 = g[2], v3 = g[3], v4 = g[4], v5 = g[5];
        x[0] = v0.x; y[0] = v0.y; z[0] = v0.z;
        x[1] = v0.w; y[1] = v1.x; z[1] = v1.y;
        x[2] = v1.z; y[2] = v1.w; z[2] = v2.x;
        x[3] = v2.y; y[3] = v2.z; z[3] = v2.w;
        x[4] = v3.x; y[4] = v3.y; z[4] = v3.z;
        x[5] = v3.w; y[5] = v4.x; z[5] = v4.y;
        x[6] = v4.z; y[6] = v4.w; z[6] = v5.x;
        x[7] = v5.y; y[7] = v5.z; z[7] = v5.w;
    }
#pragma unroll
    for (int k = 0; k < 8; ++k) dist[k] = 1e10f;
    const int lane = t & 63;
    const int wid  = t >> 6;
    const int base = t * 8;
    int far = 0;
    __syncthreads();

    for (int it = 0; it < NPTS; ++it) {
        if (t == 0) lds_cent[it & 31] = far;
        if (t == 192 && it && !(it & 15)) {        // flush prev 16 entries
            const int bi = it - 16;
            const int4* lp = (const int4*)(lds_cent + (bi & 31));
            const int4 a0 = lp[0], a1 = lp[1], a2 = lp[2], a3 = lp[3];
            int4* gp = (int4*)(cent + b * NPTS + bi);
            gp[0] = a0; gp[1] = a1; gp[2] = a2; gp[3] = a3;
            __hip_atomic_store(&prog[b * 16], it, __ATOMIC_RELEASE,
                               __HIP_MEMORY_SCOPE_AGENT);
        }
        const float4 c = sc[far];            // broadcast ds_read_b128
        float d[8];
#pragma unroll
        for (int k = 0; k < 8; ++k) {
            const float dx = x[k] - c.x;
            const float dy = y[k] - c.y;
            const float dz = z[k] - c.z;
            const float dd = __fadd_rn(__fadd_rn(__fmul_rn(dx, dx), __fmul_rn(dy, dy)),
                                       __fmul_rn(dz, dz));
            const float nd = fminf(dist[k], dd);
            dist[k] = nd;
            d[k] = nd;
        }
        float v0 = d[0]; int i0 = 0;
        if (d[1] > v0) { v0 = d[1]; i0 = 1; }
        float v1 = d[2]; int i1 = 2;
        if (d[3] > v1) { v1 = d[3]; i1 = 3; }
        float v2 = d[4]; int i2 = 4;
        if (d[5] > v2) { v2 = d[5]; i2 = 5; }
        float v3 = d[6]; int i3 = 6;
        if (d[7] > v3) { v3 = d[7]; i3 = 7; }
        if (v1 > v0) { v0 = v1; i0 = i1; }
        if (v3 > v2) { v2 = v3; i2 = i3; }
        if (v2 > v0) { v0 = v2; i0 = i2; }
        const unsigned ub = __float_as_uint(v0);
        const unsigned wm = (unsigned)__builtin_amdgcn_readlane((int)wave_max_dpp(ub), 63);
        const unsigned long long tied = __ballot(ub == wm);
        const int lolane = (int)__builtin_ctzll(tied);
        const int widx = __builtin_amdgcn_readlane(base + i0, lolane);
        if (lane == 0)
            slot[(it & 1) * 8 + wid] =
                ((unsigned long long)wm << 32) | (unsigned)(NN - 1 - widx);
        __syncthreads();
        const ulonglong2* sp = (const ulonglong2*)(slot + (it & 1) * 8);
        const ulonglong2 p0 = sp[0], p1 = sp[1], p2 = sp[2], p3 = sp[3];
        unsigned long long mk = p0.x;
        mk = p0.y > mk ? p0.y : mk;
        mk = p1.x > mk ? p1.x : mk;
        mk = p1.y > mk ? p1.y : mk;
        mk = p2.x > mk ? p2.x : mk;
        mk = p2.y > mk ? p2.y : mk;
        mk = p3.x > mk ? p3.x : mk;
        mk = p3.y > mk ? p3.y : mk;
        far = NN - 1 - (int)(mk & 0xffffffffull);
    }
    if (t == 192) {                                // tail: entries 496..511
        const int4* lp = (const int4*)(lds_cent + (496 & 31));
        const int4 a0 = lp[0], a1 = lp[1], a2 = lp[2], a3 = lp[3];
        int4* gp = (int4*)(cent + b * NPTS + 496);
        gp[0] = a0; gp[1] = a1; gp[2] = a2; gp[3] = a3;
        __hip_atomic_store(&prog[b * 16], NPTS, __ATOMIC_RELEASE,
                           __HIP_MEMORY_SCOPE_AGENT);
    }
}

// ---------------------------------------------------------------------------
// Ball query for one sample by one wave (validated bit-exact rounds 1-6).
// ---------------------------------------------------------------------------
__device__ void ball_one(const float* __restrict__ coord, int ci,
                         float* __restrict__ gout, int gw, int lane) {
    const int b = gw >> 9;
    const float* cb = coord + (size_t)b * NN * 3;
    const float sxv = cb[ci * 3 + 0], syv = cb[ci * 3 + 1], szv = cb[ci * 3 + 2];
    const float ssum = __fadd_rn(__fadd_rn(__fmul_rn(sxv, sxv), __fmul_rn(syv, syv)),
                                 __fmul_rn(szv, szv));
    float* out = gout + (size_t)gw * NSAMP;
    int total = 0;
    int first = 0;
    for (int c = 0; c < NN / 64; ++c) {
        const int p = c * 64 + lane;
        const float cx = cb[p * 3 + 0], cyv = cb[p * 3 + 1], cz = cb[p * 3 + 2];
        const float csum = __fadd_rn(__fadd_rn(__fmul_rn(cx, cx), __fmul_rn(cyv, cyv)),
                                     __fmul_rn(cz, cz));
        const float dot = __fadd_rn(__fadd_rn(__fmul_rn(sxv, cx), __fmul_rn(syv, cyv)),
                                    __fmul_rn(szv, cz));
        float dq = __fmul_rn(-2.0f, dot);
        dq = __fadd_rn(dq, ssum);
        dq = __fadd_rn(dq, csum);
        const bool keep = !(dq > 0.16f);
        const unsigned long long mask = __ballot(keep);
        if (total == 0 && mask) first = c * 64 + (int)__builtin_ctzll(mask);
        if (keep) {
            const int rank = total + __popcll(mask & ((1ull << lane) - 1ull));
            if (rank < NSAMP) out[rank] = (float)p;
        }
        total += (int)__popcll(mask);
        if (total >= NSAMP) break;
    }
    if (total < NSAMP) {
        for (int pos = total + lane; pos < NSAMP; pos += 64) out[pos] = (float)first;
    }
}

template <int C>
__device__ void stats_rows(const float* __restrict__ Y, float* __restrict__ stats,
                           int wb, float* red) {
    const int t = threadIdx.x;
    const int lane = t & 63, wv = t >> 6;
    for (int rid = wb; rid < NB * C; rid += NWRK) {
        const float4* row = (const float4*)(Y + (size_t)rid * NN);
        const float4 va = row[t], vb = row[t + 512];
        float s  = va.x + va.y + va.z + va.w + vb.x + vb.y + vb.z + vb.w;
        float s2 = va.x * va.x + va.y * va.y + va.z * va.z + va.w * va.w +
                   vb.x * vb.x + vb.y * vb.y + vb.z * vb.z + vb.w * vb.w;
#pragma unroll
        for (int m = 1; m < 64; m <<= 1) { s += __shfl_xor(s, m); s2 += __shfl_xor(s2, m); }
        if (lane == 0) { red[wv] = s; red[8 + wv] = s2; }
        __syncthreads();
        if (t == 0) {
            float S = 0.0f, S2 = 0.0f;
            for (int w = 0; w < 8; ++w) { S += red[w]; S2 += red[8 + w]; }
            atomicAdd(&stats[2 * (rid & (C - 1))], S);
            atomicAdd(&stats[2 * (rid & (C - 1)) + 1], S2);
        }
        __syncthreads();
    }
}

// ---------------------------------------------------------------------------
// Worker body (blocks 16..143): MLP chain + stats + BN apply, then ball query
// consuming cent chunks as fps publishes prog (acquire-poll, 16 lines total).
// ---------------------------------------------------------------------------
__device__ void worker_body(const float* __restrict__ coord,
                            const float* __restrict__ w0, const float* __restrict__ b0,
                            const float* __restrict__ g0, const float* __restrict__ be0,
                            const float* __restrict__ w1, const float* __restrict__ b1,
                            const float* __restrict__ g1, const float* __restrict__ be1,
                            const float* __restrict__ w2, const float* __restrict__ b2,
                            const float* __restrict__ g2, const float* __restrict__ be2,
                            float* a1, float* a2, float* feats, float* gout,
                            float* stats1, float* stats2, float* stats3,
                            int* arrive, const int* cent, const int* prog,
                            unsigned char* sm) {
    float* sW  = (float*)sm;
    float* sB  = (float*)(sm + 32768);
    float* sAC = (float*)(sm + 33280);
    float* red = (float*)(sm + 34304);
    const int t = threadIdx.x;
    const int wb = blockIdx.x - NFPS;
    const int gtid = wb * 512 + t;
    const int b = gtid >> 12, n = gtid & 4095;
    int phase = 0;

    // ---- L1: 3 -> 64
    for (int i = t; i < 64 * 3; i += 512) sW[i] = w0[i];
    if (t < 64) sB[t] = b0[t];
    __syncthreads();
    {
        const float x0 = coord[(size_t)gtid * 3 + 0];
        const float x1 = coord[(size_t)gtid * 3 + 1];
        const float x2 = coord[(size_t)gtid * 3 + 2];
        float* outp = a1 + (size_t)b * 64 * NN + n;
#pragma unroll 4
        for (int co = 0; co < 64; ++co) {
            float acc = sB[co];
            acc = fmaf(x0, sW[co * 3 + 0], acc);
            acc = fmaf(x1, sW[co * 3 + 1], acc);
            acc = fmaf(x2, sW[co * 3 + 2], acc);
            outp[(size_t)co * NN] = acc;
        }
    }
    gbar(arrive, NWRK * ++phase);
    stats_rows<64>(a1, stats1, wb, red);
    gbar(arrive, NWRK * ++phase);

    // ---- L2: 64 -> 64 (BN1+ReLU fused on load)
    for (int i = t; i < 64 * 64; i += 512) sW[i] = w1[i];
    if (t < 64) sB[t] = b1[t];
    if (t >= 256 && t < 320) {
        const int c = t - 256;
        const float mean = stats1[2 * c] * INV_BN;
        const float var  = stats1[2 * c + 1] * INV_BN - mean * mean;
        const float A = g0[c] * rsqrtf(var + BN_EPS);
        sAC[2 * c] = A;
        sAC[2 * c + 1] = be0[c] - mean * A;
    }
    __syncthreads();
    {
        float xv[64];
        const float* in0 = a1 + (size_t)b * 64 * NN + n;
#pragma unroll
        for (int ci = 0; ci < 64; ++ci) {
            const float v = in0[(size_t)ci * NN];
            xv[ci] = fmaxf(fmaf(v, sAC[2 * ci], sAC[2 * ci + 1]), 0.0f);
        }
        float* outp = a2 + (size_t)b * 64 * NN + n;
#pragma unroll 2
        for (int co = 0; co < 64; ++co) {
            float acc = sB[co];
#pragma unroll
            for (int ci = 0; ci < 64; ++ci) acc = fmaf(xv[ci], sW[co * 64 + ci], acc);
            outp[(size_t)co * NN] = acc;
        }
    }
    gbar(arrive, NWRK * ++phase);
    stats_rows<64>(a2, stats2, wb, red);
    gbar(arrive, NWRK * ++phase);

    // ---- L3: 64 -> 128 (BN2+ReLU fused on load)
    for (int i = t; i < 128 * 64; i += 512) sW[i] = w2[i];
    if (t < 128) sB[t] = b2[t];
    if (t >= 256 && t < 320) {
        const int c = t - 256;
        const float mean = stats2[2 * c] * INV_BN;
        const float var  = stats2[2 * c + 1] * INV_BN - mean * mean;
        const float A = g1[c] * rsqrtf(var + BN_EPS);
        sAC[2 * c] = A;
        sAC[2 * c + 1] = be1[c] - mean * A;
    }
    __syncthreads();
    {
        float xv[64];
        const float* in0 = a2 + (size_t)b * 64 * NN + n;
#pragma unroll
        for (int ci = 0; ci < 64; ++ci) {
            const float v = in0[(size_t)ci * NN];
            xv[ci] = fmaxf(fmaf(v, sAC[2 * ci], sAC[2 * ci + 1]), 0.0f);
        }
        float* outp = feats + (size_t)b * 128 * NN + n;
#pragma unroll 2
        for (int co = 0; co < 128; ++co) {
            float acc = sB[co];
#pragma unroll
            for (int ci = 0; ci < 64; ++ci) acc = fmaf(xv[ci], sW[co * 64 + ci], acc);
            outp[(size_t)co * NN] = acc;
        }
    }
    gbar(arrive, NWRK * ++phase);
    stats_rows<128>(feats, stats3, wb, red);
    gbar(arrive, NWRK * ++phase);

    // ---- BN3 + ReLU apply (in place on feats)
    if (t < 128) {
        const float mean = stats3[2 * t] * INV_BN;
        const float var  = stats3[2 * t + 1] * INV_BN - mean * mean;
        const float A = g2[t] * rsqrtf(var + BN_EPS);
        sAC[2 * t] = A;
        sAC[2 * t + 1] = be2[t] - mean * A;
    }
    __syncthreads();
    {
        float4* F = (float4*)feats;
        for (int i = gtid; i < NB * 128 * (NN / 4); i += NWRK * 512) {
            const int c = (i >> 10) & 127;
            const float A = sAC[2 * c], Bc = sAC[2 * c + 1];
            float4 v = F[i];
            v.x = fmaxf(fmaf(v.x, A, Bc), 0.0f);
            v.y = fmaxf(fmaf(v.y, A, Bc), 0.0f);
            v.z = fmaxf(fmaf(v.z, A, Bc), 0.0f);
            v.w = fmaxf(fmaf(v.w, A, Bc), 0.0f);
            F[i] = v;
        }
    }

    // ---- Ball query: acquire-poll per-batch progress, then consume.
    const int wvg = wb * 8 + (t >> 6);     // [0,1024)
    const int lane = t & 63;
#pragma unroll 1
    for (int j = 0; j < 8; ++j) {
        const int gw = wvg * 8 + j;
        const int bb = gw >> 9, ss = gw & 511;
        int v = 0;
        if (lane == 0) {
            while (__hip_atomic_load(&prog[bb * 16], __ATOMIC_ACQUIRE,
                                     __HIP_MEMORY_SCOPE_AGENT) <= ss)
                __builtin_amdgcn_s_sleep(16);
            v = __hip_atomic_load(&cent[bb * NPTS + ss], __ATOMIC_RELAXED,
                                  __HIP_MEMORY_SCOPE_AGENT);
        }
        v = __shfl(v, 0);
        ball_one(coord, v, gout, gw, lane);
    }
}

__global__ __launch_bounds__(512) void mega_kernel(
        const float* __restrict__ coord,
        const float* __restrict__ w0, const float* __restrict__ b0,
        const float* __restrict__ g0, const float* __restrict__ be0,
        const float* __restrict__ w1, const float* __restrict__ b1,
        const float* __restrict__ g1, const float* __restrict__ be1,
        const float* __restrict__ w2, const float* __restrict__ b2,
        const float* __restrict__ g2, const float* __restrict__ be2,
        float* a1, float* a2, float* feats, float* gout,
        float* stats1, float* stats2, float* stats3,
        int* arrive, int* cent, int* prog) {
    __shared__ __align__(16) unsigned char smem[SMEM_BYTES];
    if (blockIdx.x < NFPS) {
        fps_body(coord, cent, prog, smem);
    } else {
        worker_body(coord, w0, b0, g0, be0, w1, b1, g1, be1, w2, b2, g2, be2,
                    a1, a2, feats, gout, stats1, stats2, stats3,
                    arrive, cent, prog, smem);
    }
}

extern "C" void kernel_launch(void* const* d_in, const int* in_sizes, int n_in,
                              void* d_out, int out_size, void* d_ws, size_t ws_size,
                              hipStream_t stream) {
    const float* coord = (const float*)d_in[0];
    const float* w0  = (const float*)d_in[1];
    const float* b0  = (const float*)d_in[2];
    const float* g0  = (const float*)d_in[3];
    const float* be0 = (const float*)d_in[4];
    const float* w1  = (const float*)d_in[5];
    const float* b1  = (const float*)d_in[6];
    const float* g1  = (const float*)d_in[7];
    const float* be1 = (const float*)d_in[8];
    const float* w2  = (const float*)d_in[9];
    const float* b2  = (const float*)d_in[10];
    const float* g2  = (const float*)d_in[11];
    const float* be2 = (const float*)d_in[12];

    float* ws = (float*)d_ws;
    float* stats1 = ws;                  // 128 floats
    float* stats2 = ws + 128;            // 128
    float* stats3 = ws + 256;            // 256
    int*   arrive = (int*)(ws + 512);
    int*   prog   = (int*)(ws + 768);    // 16 counters, 64B stride
    int*   cent   = (int*)(ws + 1024);   // 8192 ints
    float* a1 = (float*)((char*)d_ws + 65536);     // 16MB
    float* a2 = a1 + (size_t)NB * 64 * NN;         // 16MB

    float* gout  = (float*)d_out;
    float* feats = (float*)d_out + (size_t)NB * NPTS * NSAMP;

    // zero stats + arrive + prog + cent
    hipMemsetAsync(d_ws, 0, 40960, stream);

    mega_kernel<<<NBLK, 512, 0, stream>>>(
        coord, w0, b0, g0, be0, w1, b1, g1, be1, w2, b2, g2, be2,
        a1, a2, feats, gout, stats1, stats2, stats3, arrive, cent, prog);
}

// Round 10
// 405.594 us; speedup vs baseline: 1.3891x; 1.3891x over previous
//
#include <hip/hip_runtime.h>
#include <hip/hip_bf16.h>

#define NB 16
#define NN 4096
#define NPTS 512
#define NSAMP 64
#define BN_EPS 1e-5f
#define INV_BN (1.0f / 65536.0f)
#define NFPS 16
#define NWRK 128
#define NBLK (NFPS + NWRK)

// 82 KB LDS/block -> 1 block/CU guaranteed (2x82 > 160KB).
// fps: [0,65536) float4 coords + [65536,65664) slots.
// workers: [0,32768) W, +32768 bias, +33280 AC, +34304 red.
#define SMEM_BYTES 83968

__device__ __forceinline__ void gbar(int* arrive, int target) {
    __syncthreads();
    if (threadIdx.x == 0) {
        __threadfence();
        atomicAdd(arrive, 1);
        while (__hip_atomic_load(arrive, __ATOMIC_RELAXED,
                                 __HIP_MEMORY_SCOPE_AGENT) < target)
            __builtin_amdgcn_s_sleep(2);
        __threadfence();
    }
    __syncthreads();
}

// wave64 unsigned-max via DPP: row_shr 1/2/4/8 + row_bcast 15/31.
// bound_ctrl=true fills 0 (identity for unsigned max). Valid in lane 63.
__device__ __forceinline__ unsigned wave_max_dpp(unsigned x) {
    unsigned o;
    o = (unsigned)__builtin_amdgcn_mov_dpp((int)x, 0x111, 0xF, 0xF, true); x = o > x ? o : x;
    o = (unsigned)__builtin_amdgcn_mov_dpp((int)x, 0x112, 0xF, 0xF, true); x = o > x ? o : x;
    o = (unsigned)__builtin_amdgcn_mov_dpp((int)x, 0x114, 0xF, 0xF, true); x = o > x ? o : x;
    o = (unsigned)__builtin_amdgcn_mov_dpp((int)x, 0x118, 0xF, 0xF, true); x = o > x ? o : x;
    o = (unsigned)__builtin_amdgcn_mov_dpp((int)x, 0x142, 0xF, 0xF, true); x = o > x ? o : x;
    o = (unsigned)__builtin_amdgcn_mov_dpp((int)x, 0x143, 0xF, 0xF, true); x = o > x ? o : x;
    return x;
}

// ---------------------------------------------------------------------------
// FPS (blocks 0..15): EXACT round-5 structure (proven 418 us mega).
// 8 waves x 8 pts/thread, contiguous mapping (lane order == index order).
// Exact numpy semantics: _rn dist ops, strict-> first-occurrence argmax,
// key (dist<<32)|(4095-idx). cent published per step as idx+1 with relaxed
// agent-scope store by t0 (cheap; pollers spread over 8192 entries).
// ---------------------------------------------------------------------------
__device__ void fps_body(const float* __restrict__ coord, int* __restrict__ cent,
                         unsigned char* sm) {
    float4* sc = (float4*)sm;
    unsigned long long* slot = (unsigned long long*)(sm + 65536);  // [2][8]
    const int b = blockIdx.x;
    const float* cb = coord + (size_t)b * NN * 3;
    const int t = threadIdx.x;

    for (int i = t; i < NN; i += 512)
        sc[i] = make_float4(cb[3 * i], cb[3 * i + 1], cb[3 * i + 2], 0.0f);

    float x[8], y[8], z[8], dist[8];
    {
        const float4* g = (const float4*)(cb + 24 * t);   // 96B, 16B-aligned
        const float4 v0 = g[0], v1 = g[1], v2 = g[2], v3 = g[3], v4 = g[4], v5 = g[5];
        x[0] = v0.x; y[0] = v0.y; z[0] = v0.z;
        x[1] = v0.w; y[1] = v1.x; z[1] = v1.y;
        x[2] = v1.z; y[2] = v1.w; z[2] = v2.x;
        x[3] = v2.y; y[3] = v2.z; z[3] = v2.w;
        x[4] = v3.x; y[4] = v3.y; z[4] = v3.z;
        x[5] = v3.w; y[5] = v4.x; z[5] = v4.y;
        x[6] = v4.z; y[6] = v4.w; z[6] = v5.x;
        x[7] = v5.y; y[7] = v5.z; z[7] = v5.w;
    }
#pragma unroll
    for (int k = 0; k < 8; ++k) dist[k] = 1e10f;
    const int lane = t & 63;
    const int wid  = t >> 6;
    const int base = t * 8;
    int far = 0;
    __syncthreads();

    for (int it = 0; it < NPTS; ++it) {
        if (t == 0)
            __hip_atomic_store(&cent[b * NPTS + it], far + 1,
                               __ATOMIC_RELAXED, __HIP_MEMORY_SCOPE_AGENT);
        const float4 c = sc[far];            // broadcast ds_read_b128
        float d[8];
#pragma unroll
        for (int k = 0; k < 8; ++k) {
            const float dx = x[k] - c.x;
            const float dy = y[k] - c.y;
            const float dz = z[k] - c.z;
            const float dd = __fadd_rn(__fadd_rn(__fmul_rn(dx, dx), __fmul_rn(dy, dy)),
                                       __fmul_rn(dz, dz));
            const float nd = fminf(dist[k], dd);
            dist[k] = nd;
            d[k] = nd;
        }
        float v0 = d[0]; int i0 = 0;
        if (d[1] > v0) { v0 = d[1]; i0 = 1; }
        float v1 = d[2]; int i1 = 2;
        if (d[3] > v1) { v1 = d[3]; i1 = 3; }
        float v2 = d[4]; int i2 = 4;
        if (d[5] > v2) { v2 = d[5]; i2 = 5; }
        float v3 = d[6]; int i3 = 6;
        if (d[7] > v3) { v3 = d[7]; i3 = 7; }
        if (v1 > v0) { v0 = v1; i0 = i1; }
        if (v3 > v2) { v2 = v3; i2 = i3; }
        if (v2 > v0) { v0 = v2; i0 = i2; }
        const unsigned ub = __float_as_uint(v0);
        const unsigned wm = (unsigned)__builtin_amdgcn_readlane((int)wave_max_dpp(ub), 63);
        const unsigned long long tied = __ballot(ub == wm);
        const int lolane = (int)__builtin_ctzll(tied);
        const int widx = __builtin_amdgcn_readlane(base + i0, lolane);
        if (lane == 0)
            slot[(it & 1) * 8 + wid] =
                ((unsigned long long)wm << 32) | (unsigned)(NN - 1 - widx);
        __syncthreads();
        const ulonglong2* sp = (const ulonglong2*)(slot + (it & 1) * 8);
        const ulonglong2 p0 = sp[0], p1 = sp[1], p2 = sp[2], p3 = sp[3];
        unsigned long long mk = p0.x;
        mk = p0.y > mk ? p0.y : mk;
        mk = p1.x > mk ? p1.x : mk;
        mk = p1.y > mk ? p1.y : mk;
        mk = p2.x > mk ? p2.x : mk;
        mk = p2.y > mk ? p2.y : mk;
        mk = p3.x > mk ? p3.x : mk;
        mk = p3.y > mk ? p3.y : mk;
        far = NN - 1 - (int)(mk & 0xffffffffull);
    }
}

// ---------------------------------------------------------------------------
// Ball query for one sample by one wave (validated bit-exact rounds 1-8).
// ---------------------------------------------------------------------------
__device__ void ball_one(const float* __restrict__ coord, int ci,
                         float* __restrict__ gout, int gw, int lane) {
    const int b = gw >> 9;
    const float* cb = coord + (size_t)b * NN * 3;
    const float sxv = cb[ci * 3 + 0], syv = cb[ci * 3 + 1], szv = cb[ci * 3 + 2];
    const float ssum = __fadd_rn(__fadd_rn(__fmul_rn(sxv, sxv), __fmul_rn(syv, syv)),
                                 __fmul_rn(szv, szv));
    float* out = gout + (size_t)gw * NSAMP;
    int total = 0;
    int first = 0;
    for (int c = 0; c < NN / 64; ++c) {
        const int p = c * 64 + lane;
        const float cx = cb[p * 3 + 0], cyv = cb[p * 3 + 1], cz = cb[p * 3 + 2];
        const float csum = __fadd_rn(__fadd_rn(__fmul_rn(cx, cx), __fmul_rn(cyv, cyv)),
                                     __fmul_rn(cz, cz));
        const float dot = __fadd_rn(__fadd_rn(__fmul_rn(sxv, cx), __fmul_rn(syv, cyv)),
                                    __fmul_rn(szv, cz));
        float dq = __fmul_rn(-2.0f, dot);
        dq = __fadd_rn(dq, ssum);
        dq = __fadd_rn(dq, csum);
        const bool keep = !(dq > 0.16f);
        const unsigned long long mask = __ballot(keep);
        if (total == 0 && mask) first = c * 64 + (int)__builtin_ctzll(mask);
        if (keep) {
            const int rank = total + __popcll(mask & ((1ull << lane) - 1ull));
            if (rank < NSAMP) out[rank] = (float)p;
        }
        total += (int)__popcll(mask);
        if (total >= NSAMP) break;
    }
    if (total < NSAMP) {
        for (int pos = total + lane; pos < NSAMP; pos += 64) out[pos] = (float)first;
    }
}

template <int C>
__device__ void stats_rows(const float* __restrict__ Y, float* __restrict__ stats,
                           int wb, float* red) {
    const int t = threadIdx.x;
    const int lane = t & 63, wv = t >> 6;
    for (int rid = wb; rid < NB * C; rid += NWRK) {
        const float4* row = (const float4*)(Y + (size_t)rid * NN);
        const float4 va = row[t], vb = row[t + 512];
        float s  = va.x + va.y + va.z + va.w + vb.x + vb.y + vb.z + vb.w;
        float s2 = va.x * va.x + va.y * va.y + va.z * va.z + va.w * va.w +
                   vb.x * vb.x + vb.y * vb.y + vb.z * vb.z + vb.w * vb.w;
#pragma unroll
        for (int m = 1; m < 64; m <<= 1) { s += __shfl_xor(s, m); s2 += __shfl_xor(s2, m); }
        if (lane == 0) { red[wv] = s; red[8 + wv] = s2; }
        __syncthreads();
        if (t == 0) {
            float S = 0.0f, S2 = 0.0f;
            for (int w = 0; w < 8; ++w) { S += red[w]; S2 += red[8 + w]; }
            atomicAdd(&stats[2 * (rid & (C - 1))], S);
            atomicAdd(&stats[2 * (rid & (C - 1)) + 1], S2);
        }
        __syncthreads();
    }
}

// ---------------------------------------------------------------------------
// Worker body (blocks 16..143): MLP chain + stats + BN apply, then ball query.
// ONLY change vs round 5: sample->wave mapping is stride-64 interleaved so
// each wave's 8 samples span the fps publish timeline (tail 8x -> 1x).
// ---------------------------------------------------------------------------
__device__ void worker_body(const float* __restrict__ coord,
                            const float* __restrict__ w0, const float* __restrict__ b0,
                            const float* __restrict__ g0, const float* __restrict__ be0,
                            const float* __restrict__ w1, const float* __restrict__ b1,
                            const float* __restrict__ g1, const float* __restrict__ be1,
                            const float* __restrict__ w2, const float* __restrict__ b2,
                            const float* __restrict__ g2, const float* __restrict__ be2,
                            float* a1, float* a2, float* feats, float* gout,
                            float* stats1, float* stats2, float* stats3,
                            int* arrive, const int* cent, unsigned char* sm) {
    float* sW  = (float*)sm;
    float* sB  = (float*)(sm + 32768);
    float* sAC = (float*)(sm + 33280);
    float* red = (float*)(sm + 34304);
    const int t = threadIdx.x;
    const int wb = blockIdx.x - NFPS;
    const int gtid = wb * 512 + t;
    const int b = gtid >> 12, n = gtid & 4095;
    int phase = 0;

    // ---- L1: 3 -> 64
    for (int i = t; i < 64 * 3; i += 512) sW[i] = w0[i];
    if (t < 64) sB[t] = b0[t];
    __syncthreads();
    {
        const float x0 = coord[(size_t)gtid * 3 + 0];
        const float x1 = coord[(size_t)gtid * 3 + 1];
        const float x2 = coord[(size_t)gtid * 3 + 2];
        float* outp = a1 + (size_t)b * 64 * NN + n;
#pragma unroll 4
        for (int co = 0; co < 64; ++co) {
            float acc = sB[co];
            acc = fmaf(x0, sW[co * 3 + 0], acc);
            acc = fmaf(x1, sW[co * 3 + 1], acc);
            acc = fmaf(x2, sW[co * 3 + 2], acc);
            outp[(size_t)co * NN] = acc;
        }
    }
    gbar(arrive, NWRK * ++phase);
    stats_rows<64>(a1, stats1, wb, red);
    gbar(arrive, NWRK * ++phase);

    // ---- L2: 64 -> 64 (BN1+ReLU fused on load)
    for (int i = t; i < 64 * 64; i += 512) sW[i] = w1[i];
    if (t < 64) sB[t] = b1[t];
    if (t >= 256 && t < 320) {
        const int c = t - 256;
        const float mean = stats1[2 * c] * INV_BN;
        const float var  = stats1[2 * c + 1] * INV_BN - mean * mean;
        const float A = g0[c] * rsqrtf(var + BN_EPS);
        sAC[2 * c] = A;
        sAC[2 * c + 1] = be0[c] - mean * A;
    }
    __syncthreads();
    {
        float xv[64];
        const float* in0 = a1 + (size_t)b * 64 * NN + n;
#pragma unroll
        for (int ci = 0; ci < 64; ++ci) {
            const float v = in0[(size_t)ci * NN];
            xv[ci] = fmaxf(fmaf(v, sAC[2 * ci], sAC[2 * ci + 1]), 0.0f);
        }
        float* outp = a2 + (size_t)b * 64 * NN + n;
#pragma unroll 2
        for (int co = 0; co < 64; ++co) {
            float acc = sB[co];
#pragma unroll
            for (int ci = 0; ci < 64; ++ci) acc = fmaf(xv[ci], sW[co * 64 + ci], acc);
            outp[(size_t)co * NN] = acc;
        }
    }
    gbar(arrive, NWRK * ++phase);
    stats_rows<64>(a2, stats2, wb, red);
    gbar(arrive, NWRK * ++phase);

    // ---- L3: 64 -> 128 (BN2+ReLU fused on load)
    for (int i = t; i < 128 * 64; i += 512) sW[i] = w2[i];
    if (t < 128) sB[t] = b2[t];
    if (t >= 256 && t < 320) {
        const int c = t - 256;
        const float mean = stats2[2 * c] * INV_BN;
        const float var  = stats2[2 * c + 1] * INV_BN - mean * mean;
        const float A = g1[c] * rsqrtf(var + BN_EPS);
        sAC[2 * c] = A;
        sAC[2 * c + 1] = be1[c] - mean * A;
    }
    __syncthreads();
    {
        float xv[64];
        const float* in0 = a2 + (size_t)b * 64 * NN + n;
#pragma unroll
        for (int ci = 0; ci < 64; ++ci) {
            const float v = in0[(size_t)ci * NN];
            xv[ci] = fmaxf(fmaf(v, sAC[2 * ci], sAC[2 * ci + 1]), 0.0f);
        }
        float* outp = feats + (size_t)b * 128 * NN + n;
#pragma unroll 2
        for (int co = 0; co < 128; ++co) {
            float acc = sB[co];
#pragma unroll
            for (int ci = 0; ci < 64; ++ci) acc = fmaf(xv[ci], sW[co * 64 + ci], acc);
            outp[(size_t)co * NN] = acc;
        }
    }
    gbar(arrive, NWRK * ++phase);
    stats_rows<128>(feats, stats3, wb, red);
    gbar(arrive, NWRK * ++phase);

    // ---- BN3 + ReLU apply (in place on feats)
    if (t < 128) {
        const float mean = stats3[2 * t] * INV_BN;
        const float var  = stats3[2 * t + 1] * INV_BN - mean * mean;
        const float A = g2[t] * rsqrtf(var + BN_EPS);
        sAC[2 * t] = A;
        sAC[2 * t + 1] = be2[t] - mean * A;
    }
    __syncthreads();
    {
        float4* F = (float4*)feats;
        for (int i = gtid; i < NB * 128 * (NN / 4); i += NWRK * 512) {
            const int c = (i >> 10) & 127;
            const float A = sAC[2 * c], Bc = sAC[2 * c + 1];
            float4 v = F[i];
            v.x = fmaxf(fmaf(v.x, A, Bc), 0.0f);
            v.y = fmaxf(fmaf(v.y, A, Bc), 0.0f);
            v.z = fmaxf(fmaf(v.z, A, Bc), 0.0f);
            v.w = fmaxf(fmaf(v.w, A, Bc), 0.0f);
            F[i] = v;
        }
    }

    // ---- Ball query: consume cent entries as fps publishes them.
    // Stride-64 interleave: wave wvg (batch wvg>>6) handles
    // ss = (wvg&63) + 64*j -> samples span publish order; only the j=7 group
    // arrives at fps end, so the serial tail is ~1 ball_one, not 8.
    const int wvg = wb * 8 + (t >> 6);     // [0,1024)
    const int lane = t & 63;
    const int bb = wvg >> 6;
    const int s0 = wvg & 63;
#pragma unroll 1
    for (int j = 0; j < 8; ++j) {
        const int ss = s0 + j * 64;
        const int gw = bb * NPTS + ss;
        int v = 0;
        if (lane == 0) {
            while ((v = __hip_atomic_load(&cent[gw], __ATOMIC_RELAXED,
                                          __HIP_MEMORY_SCOPE_AGENT)) == 0)
                __builtin_amdgcn_s_sleep(2);
        }
        v = __shfl(v, 0);
        ball_one(coord, v - 1, gout, gw, lane);
    }
}

__global__ __launch_bounds__(512) void mega_kernel(
        const float* __restrict__ coord,
        const float* __restrict__ w0, const float* __restrict__ b0,
        const float* __restrict__ g0, const float* __restrict__ be0,
        const float* __restrict__ w1, const float* __restrict__ b1,
        const float* __restrict__ g1, const float* __restrict__ be1,
        const float* __restrict__ w2, const float* __restrict__ b2,
        const float* __restrict__ g2, const float* __restrict__ be2,
        float* a1, float* a2, float* feats, float* gout,
        float* stats1, float* stats2, float* stats3,
        int* arrive, int* cent) {
    __shared__ __align__(16) unsigned char smem[SMEM_BYTES];
    if (blockIdx.x < NFPS) {
        fps_body(coord, cent, smem);
    } else {
        worker_body(coord, w0, b0, g0, be0, w1, b1, g1, be1, w2, b2, g2, be2,
                    a1, a2, feats, gout, stats1, stats2, stats3,
                    arrive, cent, smem);
    }
}

extern "C" void kernel_launch(void* const* d_in, const int* in_sizes, int n_in,
                              void* d_out, int out_size, void* d_ws, size_t ws_size,
                              hipStream_t stream) {
    const float* coord = (const float*)d_in[0];
    const float* w0  = (const float*)d_in[1];
    const float* b0  = (const float*)d_in[2];
    const float* g0  = (const float*)d_in[3];
    const float* be0 = (const float*)d_in[4];
    const float* w1  = (const float*)d_in[5];
    const float* b1  = (const float*)d_in[6];
    const float* g1  = (const float*)d_in[7];
    const float* be1 = (const float*)d_in[8];
    const float* w2  = (const float*)d_in[9];
    const float* b2  = (const float*)d_in[10];
    const float* g2  = (const float*)d_in[11];
    const float* be2 = (const float*)d_in[12];

    float* ws = (float*)d_ws;
    float* stats1 = ws;                  // 128 floats
    float* stats2 = ws + 128;            // 128
    float* stats3 = ws + 256;            // 256
    int*   arrive = (int*)(ws + 512);
    int*   cent   = (int*)(ws + 1024);   // 8192 ints, sentinel 0 = not ready
    float* a1 = (float*)((char*)d_ws + 65536);     // 16MB
    float* a2 = a1 + (size_t)NB * 64 * NN;         // 16MB

    float* gout  = (float*)d_out;
    float* feats = (float*)d_out + (size_t)NB * NPTS * NSAMP;

    // zero stats + arrive + cent sentinels
    hipMemsetAsync(d_ws, 0, 40960, stream);

    mega_kernel<<<NBLK, 512, 0, stream>>>(
        coord, w0, b0, g0, be0, w1, b1, g1, be1, w2, b2, g2, be2,
        a1, a2, feats, gout, stats1, stats2, stats3, arrive, cent);
}